// Round 7
// baseline (1345.582 us; speedup 1.0000x reference)
//
#include <hip/hip_runtime.h>

// SNN B=128, D0=512, T=512, dims 1024/1024/512, DECAY=0.5, THRESH=0.3
// Round 7: I1/I2 GEMM gets a 256x128 block tile (128x64 wave quadrants,
// 8x4 frags -> 64 MFMA : 16 ds_read per K-step, ratio 4:1 vs 2.67:1).
// I0 keeps the 128x128 split-A kernel. All grids M-fastest (XCD-friendly,
// round-5's low-FETCH order). XOR bank swizzle retained (conflicts = 0).

typedef __bf16 bf16;
typedef __attribute__((ext_vector_type(8))) __bf16 bf16x8;
typedef __attribute__((ext_vector_type(4))) float f32x4;

#define B_   128
#define D0_  512
#define T_   512
#define N1_  1024
#define N2_  1024
#define N3_  512
#define MFMA16(a,b,c) __builtin_amdgcn_mfma_f32_16x16x32_bf16((a),(b),(c),0,0,0)

#define GL2LDS(g, l) __builtin_amdgcn_global_load_lds( \
    (const __attribute__((address_space(1))) void*)(g), \
    (__attribute__((address_space(3))) void*)(l), 16, 0, 0)

// ---------- setup ----------

__global__ __launch_bounds__(256)
void split_w(const float* __restrict__ W, bf16* __restrict__ WTh, bf16* __restrict__ WTl,
             int K, int N)
{
    __shared__ float tile[32][33];
    const int k0 = blockIdx.x * 32, n0 = blockIdx.y * 32;
    const int tx = threadIdx.x & 31, ty = threadIdx.x >> 5;
#pragma unroll
    for (int r = 0; r < 4; ++r)
        tile[ty + r * 8][tx] = W[(size_t)(k0 + ty + r * 8) * N + n0 + tx];
    __syncthreads();
#pragma unroll
    for (int r = 0; r < 4; ++r) {
        int nl = ty + r * 8;
        float v = tile[tx][nl];
        bf16 h = (bf16)v;
        size_t o = (size_t)(n0 + nl) * K + k0 + tx;
        WTh[o] = h;
        WTl[o] = (bf16)(v - (float)h);
    }
}

__global__ __launch_bounds__(256)
void split_x_chunk(const float* __restrict__ in, bf16* __restrict__ Xh,
                   bf16* __restrict__ Xl, int t0)
{
    __shared__ float tile[32][33];
    const int b = blockIdx.z, d0 = blockIdx.x * 32, lt0 = blockIdx.y * 32;
    const int tx = threadIdx.x & 31, ty = threadIdx.x >> 5;
#pragma unroll
    for (int r = 0; r < 4; ++r) {
        int d = ty + r * 8;
        tile[d][tx] = in[((size_t)b * D0_ + d0 + d) * T_ + t0 + lt0 + tx];
    }
    __syncthreads();
#pragma unroll
    for (int r = 0; r < 4; ++r) {
        int lt = lt0 + ty + r * 8;
        float v = tile[tx][ty + r * 8];
        bf16 h = (bf16)v;
        size_t o = ((size_t)lt * B_ + b) * D0_ + d0 + tx;
        Xh[o] = h;
        Xl[o] = (bf16)(v - (float)h);
    }
}

// ---------- GEMM (split-A, 128x128 tile) for I0 ----------
// grid (M/128, N/128), M fastest.
template<int K>
__global__ __launch_bounds__(256)
void gemm_splitA(const bf16* __restrict__ Ah, const bf16* __restrict__ Al,
                 const bf16* __restrict__ WTh, const bf16* __restrict__ WTl,
                 float* __restrict__ C, int N)
{
    __shared__ bf16 sAh[128 * 32];
    __shared__ bf16 sAl[128 * 32];
    __shared__ bf16 sBh[128 * 32];
    __shared__ bf16 sBl[128 * 32];

    const int tid = threadIdx.x, lane = tid & 63, w = tid >> 6;
    const int wm = w & 1, wn = w >> 1;
    const int r15 = lane & 15, q = lane >> 4;
    const size_t mb = (size_t)blockIdx.x * 128;
    const int nb = blockIdx.y * 128;

    const int i4 = lane >> 2, c4 = lane & 3;
    const int csrc = c4 ^ ((i4 >> 1) & 3);
    const bf16* gA  = Ah  + (mb + w * 32 + i4) * K + csrc * 8;
    const bf16* gAl = Al  + (mb + w * 32 + i4) * K + csrc * 8;
    const bf16* gBh = WTh + (size_t)(nb + w * 32 + i4) * K + csrc * 8;
    const bf16* gBl = WTl + (size_t)(nb + w * 32 + i4) * K + csrc * 8;
    bf16* lA  = sAh + w * 32 * 32;
    bf16* lAl = sAl + w * 32 * 32;
    bf16* lBh = sBh + w * 32 * 32;
    bf16* lBl = sBl + w * 32 * 32;

    const int qsw = (q ^ ((r15 >> 1) & 3)) * 8;

    f32x4 acc[4][4] = {};

#pragma unroll 1
    for (int s = 0; s < K / 32; ++s) {
        const int go = s * 32;
        __syncthreads();
#pragma unroll
        for (int inst = 0; inst < 2; ++inst) {
            GL2LDS(gA  + (size_t)inst * 16 * K + go, lA  + inst * 16 * 32);
            GL2LDS(gAl + (size_t)inst * 16 * K + go, lAl + inst * 16 * 32);
            GL2LDS(gBh + (size_t)inst * 16 * K + go, lBh + inst * 16 * 32);
            GL2LDS(gBl + (size_t)inst * 16 * K + go, lBl + inst * 16 * 32);
        }
        __syncthreads();

        bf16x8 a[4], al2[4];
#pragma unroll
        for (int mi = 0; mi < 4; ++mi) {
            a[mi]   = *(const bf16x8*)(sAh + (wm * 64 + mi * 16 + r15) * 32 + qsw);
            al2[mi] = *(const bf16x8*)(sAl + (wm * 64 + mi * 16 + r15) * 32 + qsw);
        }
#pragma unroll
        for (int ni = 0; ni < 4; ++ni) {
            bf16x8 bh = *(const bf16x8*)(sBh + (wn * 64 + ni * 16 + r15) * 32 + qsw);
            bf16x8 bl = *(const bf16x8*)(sBl + (wn * 64 + ni * 16 + r15) * 32 + qsw);
#pragma unroll
            for (int mi = 0; mi < 4; ++mi) {
                acc[mi][ni] = MFMA16(a[mi],   bh, acc[mi][ni]);
                acc[mi][ni] = MFMA16(al2[mi], bh, acc[mi][ni]);
                acc[mi][ni] = MFMA16(a[mi],   bl, acc[mi][ni]);
            }
        }
    }
#pragma unroll
    for (int mi = 0; mi < 4; ++mi)
#pragma unroll
        for (int ni = 0; ni < 4; ++ni)
#pragma unroll
            for (int r = 0; r < 4; ++r)
                C[(mb + wm * 64 + mi * 16 + q * 4 + r) * N + nb + wn * 64 + ni * 16 + r15]
                    = acc[mi][ni][r];
}

// ---------- GEMM (binary A, 256x128 tile) for I1/I2 ----------
// 4 waves as 2x2 of 128x64 quadrants; per K-step per wave: 16 ds_read_b128,
// 64 MFMA (ratio 4:1). grid (M/256, N/128), M fastest.
template<int K>
__global__ __launch_bounds__(256)
void gemm_big(const bf16* __restrict__ A,
              const bf16* __restrict__ WTh, const bf16* __restrict__ WTl,
              float* __restrict__ C, int N)
{
    __shared__ bf16 sA [256 * 32];
    __shared__ bf16 sBh[128 * 32];
    __shared__ bf16 sBl[128 * 32];

    const int tid = threadIdx.x, lane = tid & 63, w = tid >> 6;
    const int wm = w & 1, wn = w >> 1;
    const int r15 = lane & 15, q = lane >> 4;
    const size_t mb = (size_t)blockIdx.x * 256;
    const int nb = blockIdx.y * 128;

    const int i4 = lane >> 2, c4 = lane & 3;
    const int csrc = c4 ^ ((i4 >> 1) & 3);
    const bf16* gA  = A   + (mb + w * 64 + i4) * K + csrc * 8;            // 4 insts
    const bf16* gBh = WTh + (size_t)(nb + w * 32 + i4) * K + csrc * 8;    // 2 insts
    const bf16* gBl = WTl + (size_t)(nb + w * 32 + i4) * K + csrc * 8;    // 2 insts
    bf16* lA  = sA  + w * 64 * 32;
    bf16* lBh = sBh + w * 32 * 32;
    bf16* lBl = sBl + w * 32 * 32;

    const int qsw = (q ^ ((r15 >> 1) & 3)) * 8;

    f32x4 acc[8][4] = {};

#pragma unroll 1
    for (int s = 0; s < K / 32; ++s) {
        const int go = s * 32;
        __syncthreads();
#pragma unroll
        for (int inst = 0; inst < 4; ++inst)
            GL2LDS(gA + (size_t)inst * 16 * K + go, lA + inst * 16 * 32);
#pragma unroll
        for (int inst = 0; inst < 2; ++inst) {
            GL2LDS(gBh + (size_t)inst * 16 * K + go, lBh + inst * 16 * 32);
            GL2LDS(gBl + (size_t)inst * 16 * K + go, lBl + inst * 16 * 32);
        }
        __syncthreads();

        bf16x8 a[8];
#pragma unroll
        for (int mi = 0; mi < 8; ++mi)
            a[mi] = *(const bf16x8*)(sA + (wm * 128 + mi * 16 + r15) * 32 + qsw);
#pragma unroll
        for (int ni = 0; ni < 4; ++ni) {
            bf16x8 bh = *(const bf16x8*)(sBh + (wn * 64 + ni * 16 + r15) * 32 + qsw);
            bf16x8 bl = *(const bf16x8*)(sBl + (wn * 64 + ni * 16 + r15) * 32 + qsw);
#pragma unroll
            for (int mi = 0; mi < 8; ++mi) {
                acc[mi][ni] = MFMA16(a[mi], bh, acc[mi][ni]);
                acc[mi][ni] = MFMA16(a[mi], bl, acc[mi][ni]);
            }
        }
    }
#pragma unroll
    for (int mi = 0; mi < 8; ++mi)
#pragma unroll
        for (int ni = 0; ni < 4; ++ni)
#pragma unroll
            for (int r = 0; r < 4; ++r)
                C[(mb + wm * 128 + mi * 16 + q * 4 + r) * N + nb + wn * 64 + ni * 16 + r15]
                    = acc[mi][ni][r];
}

// ---------- temporal scans ----------

__global__ __launch_bounds__(256)
void scan_chunk(const float* __restrict__ I, bf16* __restrict__ S,
                float* __restrict__ mem_st, bf16* __restrict__ spk_st,
                int BN, int Tc)
{
    const int i = blockIdx.x * 256 + threadIdx.x;
    float m = mem_st[i];
    float s = (float)spk_st[i];
#pragma unroll 8
    for (int t = 0; t < Tc; ++t) {
        float v = I[(size_t)t * BN + i];
        m = m * 0.5f * (1.0f - s) + v;
        s = (m > 0.3f) ? 1.0f : 0.0f;
        S[(size_t)t * BN + i] = (bf16)s;
    }
    mem_st[i] = m;
    spk_st[i] = (bf16)s;
}

__global__ __launch_bounds__(256)
void scan_chunk_out(const float* __restrict__ I, float* __restrict__ mem_st,
                    bf16* __restrict__ spk_st, float* __restrict__ outp,
                    int BN, int Tc)
{
    const int i = blockIdx.x * 256 + threadIdx.x;
    float m = mem_st[i];
    float s = (float)spk_st[i];
#pragma unroll 8
    for (int t = 0; t < Tc; ++t) {
        float v = I[(size_t)t * BN + i];
        m = m * 0.5f * (1.0f - s) + v;
        s = (m > 0.3f) ? 1.0f : 0.0f;
    }
    mem_st[i] = m;
    spk_st[i] = (bf16)s;
    if (outp) outp[i] = s;
}

extern "C" void kernel_launch(void* const* d_in, const int* in_sizes, int n_in,
                              void* d_out, int out_size, void* d_ws, size_t ws_size,
                              hipStream_t stream)
{
    const float* x  = (const float*)d_in[0];
    const float* w0 = (const float*)d_in[1];
    const float* w1 = (const float*)d_in[2];
    const float* w2 = (const float*)d_in[3];
    float* out = (float*)d_out;

    char* p = (char*)d_ws;
    float* mem0  = (float*)p;  p += (size_t)B_ * N1_ * 4;
    bf16*  spst0 = (bf16*)p;   p += (size_t)B_ * N1_ * 2;
    float* mem1  = (float*)p;  p += (size_t)B_ * N2_ * 4;
    bf16*  spst1 = (bf16*)p;   p += (size_t)B_ * N2_ * 2;
    float* mem2  = (float*)p;  p += (size_t)B_ * N3_ * 4;
    bf16*  spst2 = (bf16*)p;   p += (size_t)B_ * N3_ * 2;
    size_t stateBytes = (size_t)(p - (char*)d_ws);
    bf16* w0h = (bf16*)p;  p += (size_t)N1_ * D0_ * 2;
    bf16* w0l = (bf16*)p;  p += (size_t)N1_ * D0_ * 2;
    bf16* w1h = (bf16*)p;  p += (size_t)N2_ * N1_ * 2;
    bf16* w1l = (bf16*)p;  p += (size_t)N2_ * N1_ * 2;
    bf16* w2h = (bf16*)p;  p += (size_t)N3_ * N2_ * 2;
    bf16* w2l = (bf16*)p;  p += (size_t)N3_ * N2_ * 2;
    size_t fixedBytes = (size_t)(p - (char*)d_ws);

    // per-chunk buffers cost Tc * 1 MiB total
    int nc = 1;
    while (nc < 16 && fixedBytes + (size_t)(T_ / nc) * 1048576ull > ws_size) nc *= 2;
    const int Tc = T_ / nc;

    char* bufX  = p;
    char* bufS0 = bufX + (size_t)Tc * 262144;
    char* bufI  = bufS0 + (size_t)Tc * 262144;

    bf16*  Xh   = (bf16*)bufX;
    bf16*  Xl   = (bf16*)(bufX + (size_t)Tc * 131072);
    bf16*  spk0 = (bf16*)bufS0;
    bf16*  spk1 = (bf16*)bufX;          // Xh/Xl dead after gemm I0
    float* I    = (float*)bufI;

    hipMemsetAsync(d_ws, 0, stateBytes, stream);
    split_w<<<dim3(D0_/32, N1_/32), 256, 0, stream>>>(w0, w0h, w0l, D0_, N1_);
    split_w<<<dim3(N1_/32, N2_/32), 256, 0, stream>>>(w1, w1h, w1l, N1_, N2_);
    split_w<<<dim3(N2_/32, N3_/32), 256, 0, stream>>>(w2, w2h, w2l, N2_, N3_);

    for (int c = 0; c < nc; ++c) {
        const int t0 = c * Tc;
        const int M = Tc * B_;
        split_x_chunk<<<dim3(D0_/32, Tc/32, B_), 256, 0, stream>>>(x, Xh, Xl, t0);
        // I0 = X @ w0   [M x 512] x [512 x 1024], 3-term split, 128x128 tile
        gemm_splitA<D0_><<<dim3(M/128, N1_/128), 256, 0, stream>>>(
            Xh, Xl, w0h, w0l, I, N1_);
        scan_chunk<<<(B_*N1_)/256, 256, 0, stream>>>(I, spk0, mem0, spst0, B_*N1_, Tc);
        // I1 = spk0 @ w1  [M x 1024] x [1024 x 1024], 256x128 tile
        gemm_big<N1_><<<dim3(M/256, N2_/128), 256, 0, stream>>>(
            spk0, w1h, w1l, I, N2_);
        scan_chunk<<<(B_*N2_)/256, 256, 0, stream>>>(I, spk1, mem1, spst1, B_*N2_, Tc);
        // I2 = spk1 @ w2  [M x 1024] x [1024 x 512], 256x128 tile
        gemm_big<N2_><<<dim3(M/256, N3_/128), 256, 0, stream>>>(
            spk1, w2h, w2l, I, N3_);
        scan_chunk_out<<<(B_*N3_)/256, 256, 0, stream>>>(
            I, mem2, spst2, (c == nc - 1) ? out : nullptr, B_*N3_, Tc);
    }
}

// Round 8
// 1074.829 us; speedup vs baseline: 1.2519x; 1.2519x over previous
//
#include <hip/hip_runtime.h>

// SNN B=128, D0=512, T=512, dims 1024/1024/512, DECAY=0.5, THRESH=0.3
// Round 8: back to the 128x128 tile (round-7's 256-tile collapsed occupancy),
// MFMA shape switched 16x16x32 -> 32x32x16 (same work, ~17% less matrix-pipe
// time per K-step; 2382 vs 2075 TF ubench). XOR swizzle + M-fastest grid kept.

typedef __bf16 bf16;
typedef __attribute__((ext_vector_type(8))) __bf16 bf16x8;
typedef __attribute__((ext_vector_type(16))) float f32x16;

#define B_   128
#define D0_  512
#define T_   512
#define N1_  1024
#define N2_  1024
#define N3_  512
#define MFMA32(a,b,c) __builtin_amdgcn_mfma_f32_32x32x16_bf16((a),(b),(c),0,0,0)

#define GL2LDS(g, l) __builtin_amdgcn_global_load_lds( \
    (const __attribute__((address_space(1))) void*)(g), \
    (__attribute__((address_space(3))) void*)(l), 16, 0, 0)

// ---------- setup ----------

__global__ __launch_bounds__(256)
void split_w(const float* __restrict__ W, bf16* __restrict__ WTh, bf16* __restrict__ WTl,
             int K, int N)
{
    __shared__ float tile[32][33];
    const int k0 = blockIdx.x * 32, n0 = blockIdx.y * 32;
    const int tx = threadIdx.x & 31, ty = threadIdx.x >> 5;
#pragma unroll
    for (int r = 0; r < 4; ++r)
        tile[ty + r * 8][tx] = W[(size_t)(k0 + ty + r * 8) * N + n0 + tx];
    __syncthreads();
#pragma unroll
    for (int r = 0; r < 4; ++r) {
        int nl = ty + r * 8;
        float v = tile[tx][nl];
        bf16 h = (bf16)v;
        size_t o = (size_t)(n0 + nl) * K + k0 + tx;
        WTh[o] = h;
        WTl[o] = (bf16)(v - (float)h);
    }
}

__global__ __launch_bounds__(256)
void split_x_chunk(const float* __restrict__ in, bf16* __restrict__ Xh,
                   bf16* __restrict__ Xl, int t0)
{
    __shared__ float tile[32][33];
    const int b = blockIdx.z, d0 = blockIdx.x * 32, lt0 = blockIdx.y * 32;
    const int tx = threadIdx.x & 31, ty = threadIdx.x >> 5;
#pragma unroll
    for (int r = 0; r < 4; ++r) {
        int d = ty + r * 8;
        tile[d][tx] = in[((size_t)b * D0_ + d0 + d) * T_ + t0 + lt0 + tx];
    }
    __syncthreads();
#pragma unroll
    for (int r = 0; r < 4; ++r) {
        int lt = lt0 + ty + r * 8;
        float v = tile[tx][ty + r * 8];
        bf16 h = (bf16)v;
        size_t o = ((size_t)lt * B_ + b) * D0_ + d0 + tx;
        Xh[o] = h;
        Xl[o] = (bf16)(v - (float)h);
    }
}

// ---------- GEMM: C[M][N] = A[M][K] @ WT[N][K]^T, 128x128 tile, 32x32x16 MFMA ----
// 4 waves (2x2), wave tile 64x64 = 2x2 of 32x32 MFMA tiles, BK=32 (two k16 halves).
// Per wave per K-step: 12 ds_read_b128 (8 for non-split... 12 w/ hi+lo B), 16 MFMA
// (24 for SPLITA). LDS slot p of row r holds global 16B-chunk p ^ ((r>>1)&3).
// grid (M/128, N/128), M fastest.
template<int K, bool SPLITA>
__global__ __launch_bounds__(256)
void gemm32(const bf16* __restrict__ Ah, const bf16* __restrict__ Al,
            const bf16* __restrict__ WTh, const bf16* __restrict__ WTl,
            float* __restrict__ C, int N)
{
    __shared__ bf16 sAh[128 * 32];
    __shared__ bf16 sAl[SPLITA ? 128 * 32 : 16];
    __shared__ bf16 sBh[128 * 32];
    __shared__ bf16 sBl[128 * 32];

    const int tid = threadIdx.x, lane = tid & 63, w = tid >> 6;
    const int wm = w & 1, wn = w >> 1;
    const int l31 = lane & 31, kh = lane >> 5;
    const size_t mb = (size_t)blockIdx.x * 128;
    const int nb = blockIdx.y * 128;

    // staging: wave w covers tile rows [w*32, w*32+32), 2 insts of 16 rows each;
    // lane -> (row = lane>>2, chunk = lane&3); source chunk XOR-swizzled by row.
    const int i4 = lane >> 2, c4 = lane & 3;
    const int csrc = c4 ^ ((i4 >> 1) & 3);
    const bf16* gA  = Ah  + (mb + w * 32 + i4) * K + csrc * 8;
    const bf16* gAl = SPLITA ? (Al + (mb + w * 32 + i4) * K + csrc * 8) : nullptr;
    const bf16* gBh = WTh + (size_t)(nb + w * 32 + i4) * K + csrc * 8;
    const bf16* gBl = WTl + (size_t)(nb + w * 32 + i4) * K + csrc * 8;
    bf16* lA  = sAh + w * 32 * 32;
    bf16* lAl = sAl + w * 32 * 32;
    bf16* lBh = sBh + w * 32 * 32;
    bf16* lBl = sBl + w * 32 * 32;

    // fragment rows and swizzled chunk offsets (chunk for k16-half h = 2h + kh)
    int rA[2], rB[2], swA[2], swB[2];
#pragma unroll
    for (int i = 0; i < 2; ++i) {
        rA[i] = wm * 64 + i * 32 + l31;
        rB[i] = wn * 64 + i * 32 + l31;
        swA[i] = (rA[i] >> 1) & 3;
        swB[i] = (rB[i] >> 1) & 3;
    }

    f32x16 acc[2][2] = {};

#pragma unroll 1
    for (int s = 0; s < K / 32; ++s) {
        const int go = s * 32;
        __syncthreads();
#pragma unroll
        for (int inst = 0; inst < 2; ++inst) {
            GL2LDS(gA + (size_t)inst * 16 * K + go, lA + inst * 16 * 32);
            if constexpr (SPLITA)
                GL2LDS(gAl + (size_t)inst * 16 * K + go, lAl + inst * 16 * 32);
            GL2LDS(gBh + (size_t)inst * 16 * K + go, lBh + inst * 16 * 32);
            GL2LDS(gBl + (size_t)inst * 16 * K + go, lBl + inst * 16 * 32);
        }
        __syncthreads();

        bf16x8 a[2][2], al2[2][2];
#pragma unroll
        for (int mi = 0; mi < 2; ++mi)
#pragma unroll
            for (int h = 0; h < 2; ++h) {
                const int off = rA[mi] * 32 + (((2 * h + kh) ^ swA[mi]) * 8);
                a[mi][h] = *(const bf16x8*)(sAh + off);
                if constexpr (SPLITA)
                    al2[mi][h] = *(const bf16x8*)(sAl + off);
            }
#pragma unroll
        for (int ni = 0; ni < 2; ++ni) {
#pragma unroll
            for (int h = 0; h < 2; ++h) {
                const int off = rB[ni] * 32 + (((2 * h + kh) ^ swB[ni]) * 8);
                bf16x8 bh = *(const bf16x8*)(sBh + off);
                bf16x8 bl = *(const bf16x8*)(sBl + off);
#pragma unroll
                for (int mi = 0; mi < 2; ++mi) {
                    acc[mi][ni] = MFMA32(a[mi][h], bh, acc[mi][ni]);
                    if constexpr (SPLITA)
                        acc[mi][ni] = MFMA32(al2[mi][h], bh, acc[mi][ni]);
                    acc[mi][ni] = MFMA32(a[mi][h], bl, acc[mi][ni]);
                }
            }
        }
    }
    // C/D layout (verified): col = lane&31, row = (reg&3) + 8*(reg>>2) + 4*(lane>>5)
#pragma unroll
    for (int mi = 0; mi < 2; ++mi)
#pragma unroll
        for (int ni = 0; ni < 2; ++ni)
#pragma unroll
            for (int r = 0; r < 16; ++r) {
                const int row = (r & 3) + 8 * (r >> 2) + 4 * kh;
                C[(mb + wm * 64 + mi * 32 + row) * N + nb + wn * 64 + ni * 32 + l31]
                    = acc[mi][ni][r];
            }
}

// ---------- temporal scans ----------

__global__ __launch_bounds__(256)
void scan_chunk(const float* __restrict__ I, bf16* __restrict__ S,
                float* __restrict__ mem_st, bf16* __restrict__ spk_st,
                int BN, int Tc)
{
    const int i = blockIdx.x * 256 + threadIdx.x;
    float m = mem_st[i];
    float s = (float)spk_st[i];
#pragma unroll 8
    for (int t = 0; t < Tc; ++t) {
        float v = I[(size_t)t * BN + i];
        m = m * 0.5f * (1.0f - s) + v;
        s = (m > 0.3f) ? 1.0f : 0.0f;
        S[(size_t)t * BN + i] = (bf16)s;
    }
    mem_st[i] = m;
    spk_st[i] = (bf16)s;
}

__global__ __launch_bounds__(256)
void scan_chunk_out(const float* __restrict__ I, float* __restrict__ mem_st,
                    bf16* __restrict__ spk_st, float* __restrict__ outp,
                    int BN, int Tc)
{
    const int i = blockIdx.x * 256 + threadIdx.x;
    float m = mem_st[i];
    float s = (float)spk_st[i];
#pragma unroll 8
    for (int t = 0; t < Tc; ++t) {
        float v = I[(size_t)t * BN + i];
        m = m * 0.5f * (1.0f - s) + v;
        s = (m > 0.3f) ? 1.0f : 0.0f;
    }
    mem_st[i] = m;
    spk_st[i] = (bf16)s;
    if (outp) outp[i] = s;
}

extern "C" void kernel_launch(void* const* d_in, const int* in_sizes, int n_in,
                              void* d_out, int out_size, void* d_ws, size_t ws_size,
                              hipStream_t stream)
{
    const float* x  = (const float*)d_in[0];
    const float* w0 = (const float*)d_in[1];
    const float* w1 = (const float*)d_in[2];
    const float* w2 = (const float*)d_in[3];
    float* out = (float*)d_out;

    char* p = (char*)d_ws;
    float* mem0  = (float*)p;  p += (size_t)B_ * N1_ * 4;
    bf16*  spst0 = (bf16*)p;   p += (size_t)B_ * N1_ * 2;
    float* mem1  = (float*)p;  p += (size_t)B_ * N2_ * 4;
    bf16*  spst1 = (bf16*)p;   p += (size_t)B_ * N2_ * 2;
    float* mem2  = (float*)p;  p += (size_t)B_ * N3_ * 4;
    bf16*  spst2 = (bf16*)p;   p += (size_t)B_ * N3_ * 2;
    size_t stateBytes = (size_t)(p - (char*)d_ws);
    bf16* w0h = (bf16*)p;  p += (size_t)N1_ * D0_ * 2;
    bf16* w0l = (bf16*)p;  p += (size_t)N1_ * D0_ * 2;
    bf16* w1h = (bf16*)p;  p += (size_t)N2_ * N1_ * 2;
    bf16* w1l = (bf16*)p;  p += (size_t)N2_ * N1_ * 2;
    bf16* w2h = (bf16*)p;  p += (size_t)N3_ * N2_ * 2;
    bf16* w2l = (bf16*)p;  p += (size_t)N3_ * N2_ * 2;
    size_t fixedBytes = (size_t)(p - (char*)d_ws);

    // per-chunk buffers cost Tc * 1 MiB total
    int nc = 1;
    while (nc < 16 && fixedBytes + (size_t)(T_ / nc) * 1048576ull > ws_size) nc *= 2;
    const int Tc = T_ / nc;

    char* bufX  = p;
    char* bufS0 = bufX + (size_t)Tc * 262144;
    char* bufI  = bufS0 + (size_t)Tc * 262144;

    bf16*  Xh   = (bf16*)bufX;
    bf16*  Xl   = (bf16*)(bufX + (size_t)Tc * 131072);
    bf16*  spk0 = (bf16*)bufS0;
    bf16*  spk1 = (bf16*)bufX;          // Xh/Xl dead after gemm I0
    float* I    = (float*)bufI;

    hipMemsetAsync(d_ws, 0, stateBytes, stream);
    split_w<<<dim3(D0_/32, N1_/32), 256, 0, stream>>>(w0, w0h, w0l, D0_, N1_);
    split_w<<<dim3(N1_/32, N2_/32), 256, 0, stream>>>(w1, w1h, w1l, N1_, N2_);
    split_w<<<dim3(N2_/32, N3_/32), 256, 0, stream>>>(w2, w2h, w2l, N2_, N3_);

    for (int c = 0; c < nc; ++c) {
        const int t0 = c * Tc;
        const int M = Tc * B_;
        split_x_chunk<<<dim3(D0_/32, Tc/32, B_), 256, 0, stream>>>(x, Xh, Xl, t0);
        // I0 = X @ w0   [M x 512] x [512 x 1024], 3-term split
        gemm32<D0_, true><<<dim3(M/128, N1_/128), 256, 0, stream>>>(
            Xh, Xl, w0h, w0l, I, N1_);
        scan_chunk<<<(B_*N1_)/256, 256, 0, stream>>>(I, spk0, mem0, spst0, B_*N1_, Tc);
        // I1 = spk0 @ w1  [M x 1024] x [1024 x 1024], 2-term (A exact)
        gemm32<N1_, false><<<dim3(M/128, N2_/128), 256, 0, stream>>>(
            spk0, nullptr, w1h, w1l, I, N2_);
        scan_chunk<<<(B_*N2_)/256, 256, 0, stream>>>(I, spk1, mem1, spst1, B_*N2_, Tc);
        // I2 = spk1 @ w2  [M x 1024] x [1024 x 512]
        gemm32<N2_, false><<<dim3(M/128, N3_/128), 256, 0, stream>>>(
            spk1, nullptr, w2h, w2l, I, N3_);
        scan_chunk_out<<<(B_*N3_)/256, 256, 0, stream>>>(
            I, mem2, spst2, (c == nc - 1) ? out : nullptr, B_*N3_, Tc);
    }
}